// Round 1
// baseline (233.004 us; speedup 1.0000x reference)
//
#include <hip/hip_runtime.h>
#include <math.h>

// Problem dims (fixed by setup_inputs)
#define NROWS 8192   // B*S = 4*2048
#define DIN   1024
#define NT    12
#define NDEP  3
#define NDEC  36     // NT*NDEP
#define NCOL  48     // 36 decision + 12 gate logits
#define NLEAF 8
#define NC    96     // NT*NLEAF
#define NH    3
#define DOUT  512
#define KSPLIT 8
#define KCHUNK 128   // DIN / KSPLIT

// ---------------------------------------------------------------------------
// Kernel 1a: partial logits.  One row per thread, K split across blockIdx.y.
// Weight loads are thread-uniform -> compiler emits scalar loads (SGPR srcs).
// part layout: [chunk][col][row]  (coalesced writes and reads)
// ---------------------------------------------------------------------------
__global__ __launch_bounds__(256) void k_logits(const float* __restrict__ x,
                                                const float* __restrict__ dw,
                                                const float* __restrict__ gw,
                                                float* __restrict__ part) {
    const int row = blockIdx.x * 256 + threadIdx.x;
    const int kc  = blockIdx.y * KCHUNK;

    float acc[NCOL];
#pragma unroll
    for (int n = 0; n < NCOL; ++n) acc[n] = 0.0f;

    const float* xr = x + (size_t)row * DIN + kc;

    for (int sub = 0; sub < KCHUNK / 32; ++sub) {
        float4 xv[8];
#pragma unroll
        for (int q = 0; q < 8; ++q)
            xv[q] = *(const float4*)(xr + sub * 32 + q * 4);

#pragma unroll
        for (int n = 0; n < NCOL; ++n) {
            const float* wr = (n < NDEC) ? (dw + (size_t)n * DIN + kc)
                                         : (gw + (size_t)(n - NDEC) * DIN + kc);
#pragma unroll
            for (int q = 0; q < 8; ++q) {
                const float4 wv = *(const float4*)(wr + sub * 32 + q * 4);
                acc[n] = fmaf(xv[q].x, wv.x, acc[n]);
                acc[n] = fmaf(xv[q].y, wv.y, acc[n]);
                acc[n] = fmaf(xv[q].z, wv.z, acc[n]);
                acc[n] = fmaf(xv[q].w, wv.w, acc[n]);
            }
        }
    }

    float* p = part + (size_t)blockIdx.y * NCOL * NROWS + row;
#pragma unroll
    for (int n = 0; n < NCOL; ++n) p[(size_t)n * NROWS] = acc[n];
}

// ---------------------------------------------------------------------------
// Kernel 1b: reduce K-partials, apply temperature/sigmoid/leaf/softmax,
// emit C[row][96] = weight[t] * leaf_prob[t][l].
// ---------------------------------------------------------------------------
__global__ __launch_bounds__(256) void k_coeff(const float* __restrict__ part,
                                               const float* __restrict__ db,
                                               const float* __restrict__ ntl,
                                               const float* __restrict__ gb,
                                               float* __restrict__ Cm) {
    const int row = blockIdx.x * 256 + threadIdx.x;

    float lg[NCOL];
#pragma unroll
    for (int n = 0; n < NCOL; ++n) {
        float s = 0.0f;
#pragma unroll
        for (int c = 0; c < KSPLIT; ++c)
            s += part[((size_t)c * NCOL + n) * NROWS + row];
        lg[n] = s;
    }

    // gate softmax over 12 trees
    float g[NT];
    float m = -1e30f;
#pragma unroll
    for (int t = 0; t < NT; ++t) {
        g[t] = lg[NDEC + t] + gb[t];
        m = fmaxf(m, g[t]);
    }
    float sum = 0.0f;
#pragma unroll
    for (int t = 0; t < NT; ++t) {
        g[t] = expf(g[t] - m);
        sum += g[t];
    }
    const float inv = 1.0f / sum;

    float* crow = Cm + (size_t)row * NC;
#pragma unroll
    for (int t = 0; t < NT; ++t) {
        float d[NDEP];
#pragma unroll
        for (int j = 0; j < NDEP; ++j) {
            // TEMPERATURE(=1.0) * softplus(logit + 0.5413)
            const float temp = logf(1.0f + expf(ntl[t * NDEP + j] + 0.5413f));
            const float z = (lg[t * NDEP + j] + db[t * NDEP + j]) / temp;
            d[j] = 1.0f / (1.0f + expf(-z));
        }
        const float w = g[t] * inv;
#pragma unroll
        for (int l = 0; l < NLEAF; ++l) {
            // leaf l: bit2 -> level0, bit1 -> level1, bit0 -> level2
            const float p0 = (l & 4) ? (1.0f - d[0]) : d[0];
            const float p1 = (l & 2) ? (1.0f - d[1]) : d[1];
            const float p2 = (l & 1) ? (1.0f - d[2]) : d[2];
            crow[t * NLEAF + l] = w * p0 * p1 * p2;
        }
    }
}

// ---------------------------------------------------------------------------
// Kernel 2: out[h][row][d] = sum_k C[row][k] * leaf[h][k][d]
// Block = 16 rows x 384 threads; thread owns one (h, d-float4) for 16 rows.
// C loads are block-uniform -> scalar loads.
// ---------------------------------------------------------------------------
__global__ __launch_bounds__(384) void k_out(const float* __restrict__ Cm,
                                             const float* __restrict__ leaf,
                                             float* __restrict__ out) {
    const int t  = threadIdx.x;
    const int h  = t >> 7;     // 0..2
    const int dq = t & 127;    // float4 index within DOUT
    const int row0 = blockIdx.x * 16;

    float4 acc[16];
#pragma unroll
    for (int r = 0; r < 16; ++r) acc[r] = make_float4(0.f, 0.f, 0.f, 0.f);

    const float* Lh   = leaf + (size_t)h * NC * DOUT + (size_t)dq * 4;
    const float* Crow = Cm + (size_t)row0 * NC;

    for (int k4 = 0; k4 < NC / 4; ++k4) {
        const float4 l0 = *(const float4*)(Lh + (size_t)(k4 * 4 + 0) * DOUT);
        const float4 l1 = *(const float4*)(Lh + (size_t)(k4 * 4 + 1) * DOUT);
        const float4 l2 = *(const float4*)(Lh + (size_t)(k4 * 4 + 2) * DOUT);
        const float4 l3 = *(const float4*)(Lh + (size_t)(k4 * 4 + 3) * DOUT);
#pragma unroll
        for (int r = 0; r < 16; ++r) {
            const float4 c4 = *(const float4*)(Crow + r * NC + k4 * 4);
            acc[r].x = fmaf(c4.x, l0.x, acc[r].x);
            acc[r].y = fmaf(c4.x, l0.y, acc[r].y);
            acc[r].z = fmaf(c4.x, l0.z, acc[r].z);
            acc[r].w = fmaf(c4.x, l0.w, acc[r].w);
            acc[r].x = fmaf(c4.y, l1.x, acc[r].x);
            acc[r].y = fmaf(c4.y, l1.y, acc[r].y);
            acc[r].z = fmaf(c4.y, l1.z, acc[r].z);
            acc[r].w = fmaf(c4.y, l1.w, acc[r].w);
            acc[r].x = fmaf(c4.z, l2.x, acc[r].x);
            acc[r].y = fmaf(c4.z, l2.y, acc[r].y);
            acc[r].z = fmaf(c4.z, l2.z, acc[r].z);
            acc[r].w = fmaf(c4.z, l2.w, acc[r].w);
            acc[r].x = fmaf(c4.w, l3.x, acc[r].x);
            acc[r].y = fmaf(c4.w, l3.y, acc[r].y);
            acc[r].z = fmaf(c4.w, l3.z, acc[r].z);
            acc[r].w = fmaf(c4.w, l3.w, acc[r].w);
        }
    }

#pragma unroll
    for (int r = 0; r < 16; ++r)
        *(float4*)(out + ((size_t)h * NROWS + row0 + r) * DOUT + (size_t)dq * 4) = acc[r];
}

extern "C" void kernel_launch(void* const* d_in, const int* in_sizes, int n_in,
                              void* d_out, int out_size, void* d_ws, size_t ws_size,
                              hipStream_t stream) {
    const float* x    = (const float*)d_in[0];
    const float* dw   = (const float*)d_in[1];
    const float* db   = (const float*)d_in[2];
    const float* ntl  = (const float*)d_in[3];
    const float* gw   = (const float*)d_in[4];
    const float* gb   = (const float*)d_in[5];
    const float* leaf = (const float*)d_in[6];
    float* out = (float*)d_out;

    float* part = (float*)d_ws;                                 // 8*48*8192 f32 = 12.6 MB
    float* Cm   = part + (size_t)KSPLIT * NCOL * NROWS;         // 8192*96 f32 = 3.1 MB

    k_logits<<<dim3(NROWS / 256, KSPLIT), 256, 0, stream>>>(x, dw, gw, part);
    k_coeff<<<NROWS / 256, 256, 0, stream>>>(part, db, ntl, gb, Cm);
    k_out<<<NROWS / 16, 384, 0, stream>>>(Cm, leaf, out);
}

// Round 2
// 61.601 us; speedup vs baseline: 3.7825x; 3.7825x over previous
//
#include <hip/hip_runtime.h>
#include <math.h>

// Problem dims (fixed by setup_inputs)
#define NROWS 8192   // B*S
#define DIN   1024
#define NT    12
#define NDEP  3
#define NDEC  36     // NT*NDEP
#define NCOL  48     // 36 decision + 12 gate logits
#define NLEAF 8
#define NC    96     // NT*NLEAF
#define NH    3
#define DOUT  512
#define KSPLIT 4
#define KCHUNK 256   // DIN / KSPLIT

typedef short bf16x8 __attribute__((ext_vector_type(8)));   // 8 bf16 = 4 VGPRs (MFMA A/B frag)
typedef float f32x4  __attribute__((ext_vector_type(4)));   // MFMA C/D frag

__device__ inline unsigned short f2bf(float f) {            // round-to-nearest-even
    unsigned u = __float_as_uint(f);
    u = u + 0x7fff + ((u >> 16) & 1);
    return (unsigned short)(u >> 16);
}
__device__ inline float bf2f(unsigned short h) {
    return __uint_as_float(((unsigned)h) << 16);
}

// ---------------------------------------------------------------------------
// Prep: combined weight matrix W[48][1024] -> bf16 hi/lo split, [n][k] layout.
// n<36: decision_weights (t*3+j ordering matches einsum 'tnd'); n>=36: gate_w.
// ---------------------------------------------------------------------------
__global__ __launch_bounds__(256) void k_prep_w(const float* __restrict__ dw,
                                                const float* __restrict__ gw,
                                                unsigned short* __restrict__ w_hi,
                                                unsigned short* __restrict__ w_lo) {
    const int i = blockIdx.x * 256 + threadIdx.x;   // n*1024 + k
    const int n = i >> 10;
    const float v = (n < NDEC) ? dw[i] : gw[i - NDEC * DIN];
    const unsigned short h = f2bf(v);
    w_hi[i] = h;
    w_lo[i] = f2bf(v - bf2f(h));
}

// ---------------------------------------------------------------------------
// Prep: leafT[h][d][k] bf16 (transposed so B-fragments read 8 contiguous k).
// thread -> (hq = h*512+d, kq = k-octet); lanes consecutive in d (coalesced).
// ---------------------------------------------------------------------------
__global__ __launch_bounds__(256) void k_prep_leaf(const float* __restrict__ leaf,
                                                   unsigned short* __restrict__ leafT) {
    const int i  = blockIdx.x * 256 + threadIdx.x;  // 0 .. 1536*12-1
    const int hq = i % (NH * DOUT);                 // h*512 + d
    const int kq = i / (NH * DOUT);                 // 0..11
    const int h  = hq >> 9, d = hq & 511;
    bf16x8 v;
#pragma unroll
    for (int e = 0; e < 8; ++e)
        v[e] = (short)f2bf(leaf[(size_t)(h * NC + kq * 8 + e) * DOUT + d]);
    *(bf16x8*)(leafT + (size_t)hq * NC + kq * 8) = v;
}

// ---------------------------------------------------------------------------
// GEMM1 (MFMA, split-bf16): part[c][row][n] += x[row][k] * W[n][k]
// Block = 4 waves; wave = 16 rows x 48 cols over K-chunk of 256.
// Products: xhi*whi + xlo*whi + xhi*wlo  (~f32 precision).
// ---------------------------------------------------------------------------
__global__ __launch_bounds__(256) void k_logits(const float* __restrict__ x,
                                                const unsigned short* __restrict__ w_hi,
                                                const unsigned short* __restrict__ w_lo,
                                                float* __restrict__ part) {
    const int wave = threadIdx.x >> 6, lane = threadIdx.x & 63;
    const int row0 = blockIdx.x * 64 + wave * 16;
    const int kc   = blockIdx.y * KCHUNK;
    const int lrow = lane & 15;            // A: m index / B: n index
    const int lk   = (lane >> 4) * 8;      // k base within 32-step

    f32x4 acc[3];
#pragma unroll
    for (int nf = 0; nf < 3; ++nf)
#pragma unroll
        for (int r = 0; r < 4; ++r) acc[nf][r] = 0.0f;

    const float* xp = x + (size_t)(row0 + lrow) * DIN + kc + lk;

    for (int ks = 0; ks < KCHUNK / 32; ++ks) {
        const float4 xa = *(const float4*)(xp + ks * 32);
        const float4 xb = *(const float4*)(xp + ks * 32 + 4);
        const float v[8] = {xa.x, xa.y, xa.z, xa.w, xb.x, xb.y, xb.z, xb.w};
        bf16x8 xhi, xlo;
#pragma unroll
        for (int e = 0; e < 8; ++e) {
            const unsigned short h = f2bf(v[e]);
            xhi[e] = (short)h;
            xlo[e] = (short)f2bf(v[e] - bf2f(h));
        }
#pragma unroll
        for (int nf = 0; nf < 3; ++nf) {
            const size_t woff = (size_t)(nf * 16 + lrow) * DIN + kc + ks * 32 + lk;
            const bf16x8 whi = *(const bf16x8*)(w_hi + woff);
            const bf16x8 wlo = *(const bf16x8*)(w_lo + woff);
            acc[nf] = __builtin_amdgcn_mfma_f32_16x16x32_bf16(xhi, whi, acc[nf], 0, 0, 0);
            acc[nf] = __builtin_amdgcn_mfma_f32_16x16x32_bf16(xlo, whi, acc[nf], 0, 0, 0);
            acc[nf] = __builtin_amdgcn_mfma_f32_16x16x32_bf16(xhi, wlo, acc[nf], 0, 0, 0);
        }
    }

    // D layout: col = lane&15 (-> n), row = (lane>>4)*4 + reg
    float* pp = part + (size_t)blockIdx.y * NROWS * NCOL;
#pragma unroll
    for (int nf = 0; nf < 3; ++nf) {
        const int n = nf * 16 + (lane & 15);
#pragma unroll
        for (int r = 0; r < 4; ++r) {
            const int row = row0 + (lane >> 4) * 4 + r;
            pp[(size_t)row * NCOL + n] = acc[nf][r];
        }
    }
}

// ---------------------------------------------------------------------------
// Reduce K-partials, epilogue (softplus/sigmoid/leaf/softmax), emit bf16
// C[row][96] = weight[t] * leaf_prob[t][l].
// ---------------------------------------------------------------------------
__global__ __launch_bounds__(256) void k_coeff(const float* __restrict__ part,
                                               const float* __restrict__ db,
                                               const float* __restrict__ ntl,
                                               const float* __restrict__ gb,
                                               unsigned short* __restrict__ Cbf) {
    const int row = blockIdx.x * 256 + threadIdx.x;

    float lg[NCOL];
#pragma unroll
    for (int n = 0; n < NCOL; ++n) lg[n] = 0.0f;
#pragma unroll
    for (int c = 0; c < KSPLIT; ++c) {
        const float* pr = part + ((size_t)c * NROWS + row) * NCOL;
#pragma unroll
        for (int q = 0; q < NCOL / 4; ++q) {
            const float4 v = *(const float4*)(pr + q * 4);
            lg[q * 4 + 0] += v.x;
            lg[q * 4 + 1] += v.y;
            lg[q * 4 + 2] += v.z;
            lg[q * 4 + 3] += v.w;
        }
    }

    // gate softmax over 12 trees
    float g[NT];
    float m = -1e30f;
#pragma unroll
    for (int t = 0; t < NT; ++t) {
        g[t] = lg[NDEC + t] + gb[t];
        m = fmaxf(m, g[t]);
    }
    float sum = 0.0f;
#pragma unroll
    for (int t = 0; t < NT; ++t) {
        g[t] = expf(g[t] - m);
        sum += g[t];
    }
    const float inv = 1.0f / sum;

    unsigned short crow[NC];
#pragma unroll
    for (int t = 0; t < NT; ++t) {
        float d[NDEP];
#pragma unroll
        for (int j = 0; j < NDEP; ++j) {
            const float temp = logf(1.0f + expf(ntl[t * NDEP + j] + 0.5413f));
            const float z = (lg[t * NDEP + j] + db[t * NDEP + j]) / temp;
            d[j] = 1.0f / (1.0f + expf(-z));
        }
        const float w = g[t] * inv;
#pragma unroll
        for (int l = 0; l < NLEAF; ++l) {
            const float p0 = (l & 4) ? (1.0f - d[0]) : d[0];
            const float p1 = (l & 2) ? (1.0f - d[1]) : d[1];
            const float p2 = (l & 1) ? (1.0f - d[2]) : d[2];
            crow[t * NLEAF + l] = f2bf(w * p0 * p1 * p2);
        }
    }
    unsigned short* cp = Cbf + (size_t)row * NC;
#pragma unroll
    for (int q = 0; q < NC / 8; ++q)
        *(bf16x8*)(cp + q * 8) = *(bf16x8*)(crow + q * 8);
}

// ---------------------------------------------------------------------------
// GEMM2 (MFMA bf16): out[h][row][d] = sum_k C[row][k] * leafT[h][d][k]
// Block = 4 waves = 64 rows x 64 cols for one h; K=96 = 3 MFMA steps.
// ---------------------------------------------------------------------------
__global__ __launch_bounds__(256) void k_out(const unsigned short* __restrict__ Cbf,
                                             const unsigned short* __restrict__ leafT,
                                             float* __restrict__ out) {
    const int wave = threadIdx.x >> 6, lane = threadIdx.x & 63;
    const int row0 = blockIdx.x * 64 + wave * 16;
    const int col0 = blockIdx.y * 64;
    const int h    = blockIdx.z;
    const int lrow = lane & 15;
    const int lk   = (lane >> 4) * 8;

    f32x4 acc[4];
#pragma unroll
    for (int nf = 0; nf < 4; ++nf)
#pragma unroll
        for (int r = 0; r < 4; ++r) acc[nf][r] = 0.0f;

#pragma unroll
    for (int ks = 0; ks < 3; ++ks) {
        const bf16x8 a = *(const bf16x8*)(Cbf + (size_t)(row0 + lrow) * NC + ks * 32 + lk);
#pragma unroll
        for (int nf = 0; nf < 4; ++nf) {
            const bf16x8 b = *(const bf16x8*)(leafT +
                (size_t)(h * DOUT + col0 + nf * 16 + lrow) * NC + ks * 32 + lk);
            acc[nf] = __builtin_amdgcn_mfma_f32_16x16x32_bf16(a, b, acc[nf], 0, 0, 0);
        }
    }

#pragma unroll
    for (int nf = 0; nf < 4; ++nf) {
        const int d = col0 + nf * 16 + (lane & 15);
#pragma unroll
        for (int r = 0; r < 4; ++r) {
            const int row = row0 + (lane >> 4) * 4 + r;
            out[((size_t)h * NROWS + row) * DOUT + d] = acc[nf][r];
        }
    }
}

extern "C" void kernel_launch(void* const* d_in, const int* in_sizes, int n_in,
                              void* d_out, int out_size, void* d_ws, size_t ws_size,
                              hipStream_t stream) {
    const float* x    = (const float*)d_in[0];
    const float* dw   = (const float*)d_in[1];
    const float* db   = (const float*)d_in[2];
    const float* ntl  = (const float*)d_in[3];
    const float* gw   = (const float*)d_in[4];
    const float* gb   = (const float*)d_in[5];
    const float* leaf = (const float*)d_in[6];
    float* out = (float*)d_out;

    // workspace carve (byte offsets, all 16B-aligned)
    char* ws = (char*)d_ws;
    float*          part  = (float*)(ws);                          // 4*8192*48*4  = 6291456 B
    unsigned short* Cbf   = (unsigned short*)(ws + 6291456);       // 8192*96*2    = 1572864 B
    unsigned short* w_hi  = (unsigned short*)(ws + 7864320);       // 48*1024*2    =   98304 B
    unsigned short* w_lo  = (unsigned short*)(ws + 7962624);       //                  98304 B
    unsigned short* leafT = (unsigned short*)(ws + 8060928);       // 3*512*96*2   =  294912 B

    k_prep_w<<<NCOL * DIN / 256, 256, 0, stream>>>(dw, gw, w_hi, w_lo);
    k_prep_leaf<<<NH * DOUT * (NC / 8) / 256, 256, 0, stream>>>(leaf, leafT);
    k_logits<<<dim3(NROWS / 64, KSPLIT), 256, 0, stream>>>(x, w_hi, w_lo, part);
    k_coeff<<<NROWS / 256, 256, 0, stream>>>(part, db, ntl, gb, Cbf);
    k_out<<<dim3(NROWS / 64, DOUT / 64, NH), 256, 0, stream>>>(Cbf, leafT, out);
}

// Round 3
// 59.982 us; speedup vs baseline: 3.8845x; 1.0270x over previous
//
#include <hip/hip_runtime.h>
#include <math.h>

// Problem dims (fixed by setup_inputs)
#define NROWS 8192   // B*S
#define DIN   1024
#define NT    12
#define NDEP  3
#define NDEC  36     // NT*NDEP
#define NCOL  48     // 36 decision + 12 gate logits
#define NLEAF 8
#define NC    96     // NT*NLEAF
#define NH    3
#define DOUT  512
#define KSPLIT 8
#define KCHUNK 128   // DIN / KSPLIT

typedef short bf16x8 __attribute__((ext_vector_type(8)));   // 8 bf16 = 4 VGPRs (MFMA A/B frag)
typedef float f32x4  __attribute__((ext_vector_type(4)));   // MFMA C/D frag

__device__ inline unsigned short f2bf(float f) {            // round-to-nearest-even
    unsigned u = __float_as_uint(f);
    u = u + 0x7fff + ((u >> 16) & 1);
    return (unsigned short)(u >> 16);
}
__device__ inline float bf2f(unsigned short h) {
    return __uint_as_float(((unsigned)h) << 16);
}

// ---------------------------------------------------------------------------
// k_prep (merged): blocks [0,192): W[48][1024] -> bf16 hi/lo split ([n][k]);
// blocks [192,264): leafT[h][d][k] bf16; block 264: param tables
// inv_temp[36] = 1/softplus(ntl+0.5413), zb[36] = db * inv_temp.
// ---------------------------------------------------------------------------
__global__ __launch_bounds__(256) void k_prep(const float* __restrict__ dw,
                                              const float* __restrict__ gw,
                                              const float* __restrict__ db,
                                              const float* __restrict__ ntl,
                                              const float* __restrict__ leaf,
                                              unsigned short* __restrict__ w_hi,
                                              unsigned short* __restrict__ w_lo,
                                              unsigned short* __restrict__ leafT,
                                              float* __restrict__ it_zb) {
    const int b = blockIdx.x;
    if (b < 192) {
        const int i = b * 256 + threadIdx.x;        // n*1024 + k
        const int n = i >> 10;
        const float v = (n < NDEC) ? dw[i] : gw[i - NDEC * DIN];
        const unsigned short h = f2bf(v);
        w_hi[i] = h;
        w_lo[i] = f2bf(v - bf2f(h));
    } else if (b < 264) {
        const int i  = (b - 192) * 256 + threadIdx.x;   // 0 .. 18431
        const int hq = i % (NH * DOUT);                 // h*512 + d
        const int kq = i / (NH * DOUT);                 // 0..11
        const int h  = hq >> 9, d = hq & 511;
        bf16x8 v;
#pragma unroll
        for (int e = 0; e < 8; ++e)
            v[e] = (short)f2bf(leaf[(size_t)(h * NC + kq * 8 + e) * DOUT + d]);
        *(bf16x8*)(leafT + (size_t)hq * NC + kq * 8) = v;
    } else {
        const int i = threadIdx.x;
        if (i < NDEC) {
            const float v  = ntl[i] + 0.5413f;
            const float sp = (v > 20.0f) ? v : logf(1.0f + expf(v));
            const float it = 1.0f / sp;
            it_zb[i]        = it;            // inv_temp
            it_zb[NDEC + i] = db[i] * it;    // pre-scaled bias
        }
    }
}

// ---------------------------------------------------------------------------
// GEMM1 (MFMA, split-bf16): part[c][row][n] = x[row][kc..]*W[n][kc..]
// Block = 4 waves; wave = 16 rows x 48 cols over a K-chunk of 128.
// Products: xhi*whi + xlo*whi + xhi*wlo  (~f32 precision).
// Grid 1024 blocks -> 4 blocks/CU -> 4 waves/SIMD for latency hiding.
// ---------------------------------------------------------------------------
__global__ __launch_bounds__(256) void k_logits(const float* __restrict__ x,
                                                const unsigned short* __restrict__ w_hi,
                                                const unsigned short* __restrict__ w_lo,
                                                float* __restrict__ part) {
    const int wave = threadIdx.x >> 6, lane = threadIdx.x & 63;
    const int row0 = blockIdx.x * 64 + wave * 16;
    const int kc   = blockIdx.y * KCHUNK;
    const int lrow = lane & 15;            // A: m index / B: n index
    const int lk   = (lane >> 4) * 8;      // k base within 32-step

    f32x4 acc[3];
#pragma unroll
    for (int nf = 0; nf < 3; ++nf)
#pragma unroll
        for (int r = 0; r < 4; ++r) acc[nf][r] = 0.0f;

    const float* xp = x + (size_t)(row0 + lrow) * DIN + kc + lk;

#pragma unroll
    for (int ks = 0; ks < KCHUNK / 32; ++ks) {
        const float4 xa = *(const float4*)(xp + ks * 32);
        const float4 xb = *(const float4*)(xp + ks * 32 + 4);
        const float v[8] = {xa.x, xa.y, xa.z, xa.w, xb.x, xb.y, xb.z, xb.w};
        bf16x8 xhi, xlo;
#pragma unroll
        for (int e = 0; e < 8; ++e) {
            const unsigned short h = f2bf(v[e]);
            xhi[e] = (short)h;
            xlo[e] = (short)f2bf(v[e] - bf2f(h));
        }
#pragma unroll
        for (int nf = 0; nf < 3; ++nf) {
            const size_t woff = (size_t)(nf * 16 + lrow) * DIN + kc + ks * 32 + lk;
            const bf16x8 whi = *(const bf16x8*)(w_hi + woff);
            const bf16x8 wlo = *(const bf16x8*)(w_lo + woff);
            acc[nf] = __builtin_amdgcn_mfma_f32_16x16x32_bf16(xhi, whi, acc[nf], 0, 0, 0);
            acc[nf] = __builtin_amdgcn_mfma_f32_16x16x32_bf16(xlo, whi, acc[nf], 0, 0, 0);
            acc[nf] = __builtin_amdgcn_mfma_f32_16x16x32_bf16(xhi, wlo, acc[nf], 0, 0, 0);
        }
    }

    // D layout: col = lane&15 (-> n), row = (lane>>4)*4 + reg
    float* pp = part + (size_t)blockIdx.y * NROWS * NCOL;
#pragma unroll
    for (int nf = 0; nf < 3; ++nf) {
        const int n = nf * 16 + (lane & 15);
#pragma unroll
        for (int r = 0; r < 4; ++r) {
            const int row = row0 + (lane >> 4) * 4 + r;
            pp[(size_t)row * NCOL + n] = acc[nf][r];
        }
    }
}

// ---------------------------------------------------------------------------
// Reduce K-partials, epilogue (sigmoid/leaf/softmax with precomputed temps),
// emit bf16 C[row][96] = weight[t] * leaf_prob[t][l].  One row per thread.
// ---------------------------------------------------------------------------
__global__ __launch_bounds__(64) void k_coeff(const float* __restrict__ part,
                                              const float* __restrict__ it_zb,
                                              const float* __restrict__ gb,
                                              unsigned short* __restrict__ Cbf) {
    const int row = blockIdx.x * 64 + threadIdx.x;

    float lg[NCOL];
#pragma unroll
    for (int n = 0; n < NCOL; ++n) lg[n] = 0.0f;
#pragma unroll
    for (int c = 0; c < KSPLIT; ++c) {
        const float* pr = part + ((size_t)c * NROWS + row) * NCOL;
#pragma unroll
        for (int q = 0; q < NCOL / 4; ++q) {
            const float4 v = *(const float4*)(pr + q * 4);
            lg[q * 4 + 0] += v.x;
            lg[q * 4 + 1] += v.y;
            lg[q * 4 + 2] += v.z;
            lg[q * 4 + 3] += v.w;
        }
    }

    // gate softmax over 12 trees
    float g[NT];
    float m = -1e30f;
#pragma unroll
    for (int t = 0; t < NT; ++t) {
        g[t] = lg[NDEC + t] + gb[t];
        m = fmaxf(m, g[t]);
    }
    float sum = 0.0f;
#pragma unroll
    for (int t = 0; t < NT; ++t) {
        g[t] = expf(g[t] - m);
        sum += g[t];
    }
    const float inv = __builtin_amdgcn_rcpf(sum);

    unsigned short crow[NC];
#pragma unroll
    for (int t = 0; t < NT; ++t) {
        float d[NDEP];
#pragma unroll
        for (int j = 0; j < NDEP; ++j) {
            const int n = t * NDEP + j;
            const float z = lg[n] * it_zb[n] + it_zb[NDEC + n];
            d[j] = __builtin_amdgcn_rcpf(1.0f + expf(-z));
        }
        const float w = g[t] * inv;
#pragma unroll
        for (int l = 0; l < NLEAF; ++l) {
            const float p0 = (l & 4) ? (1.0f - d[0]) : d[0];
            const float p1 = (l & 2) ? (1.0f - d[1]) : d[1];
            const float p2 = (l & 1) ? (1.0f - d[2]) : d[2];
            crow[t * NLEAF + l] = f2bf(w * p0 * p1 * p2);
        }
    }
    unsigned short* cp = Cbf + (size_t)row * NC;
#pragma unroll
    for (int q = 0; q < NC / 8; ++q)
        *(bf16x8*)(cp + q * 8) = *(bf16x8*)(crow + q * 8);
}

// ---------------------------------------------------------------------------
// GEMM2 (MFMA bf16): out[h][row][d] = sum_k C[row][k] * leafT[h][d][k]
// Block = 4 waves = 64 rows x 64 cols for one h; K=96 = 3 MFMA steps.
// ---------------------------------------------------------------------------
__global__ __launch_bounds__(256) void k_out(const unsigned short* __restrict__ Cbf,
                                             const unsigned short* __restrict__ leafT,
                                             float* __restrict__ out) {
    const int wave = threadIdx.x >> 6, lane = threadIdx.x & 63;
    const int row0 = blockIdx.x * 64 + wave * 16;
    const int col0 = blockIdx.y * 64;
    const int h    = blockIdx.z;
    const int lrow = lane & 15;
    const int lk   = (lane >> 4) * 8;

    f32x4 acc[4];
#pragma unroll
    for (int nf = 0; nf < 4; ++nf)
#pragma unroll
        for (int r = 0; r < 4; ++r) acc[nf][r] = 0.0f;

#pragma unroll
    for (int ks = 0; ks < 3; ++ks) {
        const bf16x8 a = *(const bf16x8*)(Cbf + (size_t)(row0 + lrow) * NC + ks * 32 + lk);
#pragma unroll
        for (int nf = 0; nf < 4; ++nf) {
            const bf16x8 b = *(const bf16x8*)(leafT +
                (size_t)(h * DOUT + col0 + nf * 16 + lrow) * NC + ks * 32 + lk);
            acc[nf] = __builtin_amdgcn_mfma_f32_16x16x32_bf16(a, b, acc[nf], 0, 0, 0);
        }
    }

#pragma unroll
    for (int nf = 0; nf < 4; ++nf) {
        const int d = col0 + nf * 16 + (lane & 15);
#pragma unroll
        for (int r = 0; r < 4; ++r) {
            const int row = row0 + (lane >> 4) * 4 + r;
            out[((size_t)h * NROWS + row) * DOUT + d] = acc[nf][r];
        }
    }
}

extern "C" void kernel_launch(void* const* d_in, const int* in_sizes, int n_in,
                              void* d_out, int out_size, void* d_ws, size_t ws_size,
                              hipStream_t stream) {
    const float* x    = (const float*)d_in[0];
    const float* dw   = (const float*)d_in[1];
    const float* db   = (const float*)d_in[2];
    const float* ntl  = (const float*)d_in[3];
    const float* gw   = (const float*)d_in[4];
    const float* gb   = (const float*)d_in[5];
    const float* leaf = (const float*)d_in[6];
    float* out = (float*)d_out;

    // workspace carve (byte offsets, all 16B-aligned)
    char* ws = (char*)d_ws;
    float*          part  = (float*)(ws);                     // 8*8192*48*4 = 12582912 B
    unsigned short* Cbf   = (unsigned short*)(ws + 12582912); // 8192*96*2   =  1572864 B
    unsigned short* w_hi  = (unsigned short*)(ws + 14155776); // 48*1024*2   =    98304 B
    unsigned short* w_lo  = (unsigned short*)(ws + 14254080); //                  98304 B
    unsigned short* leafT = (unsigned short*)(ws + 14352384); // 3*512*96*2  =   294912 B
    float*          it_zb = (float*)(ws + 14647296);          // 72*4        =      288 B

    k_prep<<<265, 256, 0, stream>>>(dw, gw, db, ntl, leaf, w_hi, w_lo, leafT, it_zb);
    k_logits<<<dim3(NROWS / 64, KSPLIT), 256, 0, stream>>>(x, w_hi, w_lo, part);
    k_coeff<<<NROWS / 64, 64, 0, stream>>>(part, it_zb, gb, Cbf);
    k_out<<<dim3(NROWS / 64, DOUT / 64, NH), 256, 0, stream>>>(Cbf, leafT, out);
}

// Round 4
// 39.088 us; speedup vs baseline: 5.9610x; 1.5345x over previous
//
#include <hip/hip_runtime.h>
#include <math.h>

// Problem dims (fixed by setup_inputs)
#define NROWS 8192   // B*S
#define DIN   1024
#define NT    12
#define NDEP  3
#define NDEC  36     // NT*NDEP
#define NCOL  48     // 36 decision + 12 gate logits
#define NC    96     // NT*NLEAF
#define NH    3
#define DOUT  512
#define CLP   104    // padded C_lds row (bf16): 96 -> 104 keeps 16B align, spreads banks

typedef short bf16x8 __attribute__((ext_vector_type(8)));   // 8 bf16 = 4 VGPRs (MFMA A/B frag)
typedef float f32x4  __attribute__((ext_vector_type(4)));   // MFMA C/D frag

__device__ inline unsigned short f2bf(float f) {            // round-to-nearest-even
    unsigned u = __float_as_uint(f);
    u = u + 0x7fff + ((u >> 16) & 1);
    return (unsigned short)(u >> 16);
}
__device__ inline float bf2f(unsigned short h) {
    return __uint_as_float(((unsigned)h) << 16);
}
// packed RTNE f32x2 -> bf16x2 (low16 = a, high16 = b)
__device__ inline unsigned cvt_pk(float a, float b) {
    unsigned r;
    asm("v_cvt_pk_bf16_f32 %0, %1, %2" : "=v"(r) : "v"(a), "v"(b));
    return r;
}
// split 8 consecutive f32 into bf16 hi + bf16 lo fragments (exact residual)
__device__ inline void split8(const float4 a, const float4 b, bf16x8& hi, bf16x8& lo) {
    union U { unsigned u[4]; bf16x8 v; };
    U H, L;
    H.u[0] = cvt_pk(a.x, a.y); H.u[1] = cvt_pk(a.z, a.w);
    H.u[2] = cvt_pk(b.x, b.y); H.u[3] = cvt_pk(b.z, b.w);
    const float r0 = a.x - __uint_as_float(H.u[0] << 16);
    const float r1 = a.y - __uint_as_float(H.u[0] & 0xffff0000u);
    const float r2 = a.z - __uint_as_float(H.u[1] << 16);
    const float r3 = a.w - __uint_as_float(H.u[1] & 0xffff0000u);
    const float r4 = b.x - __uint_as_float(H.u[2] << 16);
    const float r5 = b.y - __uint_as_float(H.u[2] & 0xffff0000u);
    const float r6 = b.z - __uint_as_float(H.u[3] << 16);
    const float r7 = b.w - __uint_as_float(H.u[3] & 0xffff0000u);
    L.u[0] = cvt_pk(r0, r1); L.u[1] = cvt_pk(r2, r3);
    L.u[2] = cvt_pk(r4, r5); L.u[3] = cvt_pk(r6, r7);
    hi = H.v; lo = L.v;
}

// ---------------------------------------------------------------------------
// k_prep (merged): blocks [0,192): W[48][1024] -> bf16 hi/lo split ([n][k]);
// blocks [192,264): leafT[h][d][k] bf16; block 264: param tables
// inv_temp[36] = 1/softplus(ntl+0.5413), zb[36] = db * inv_temp.
// ---------------------------------------------------------------------------
__global__ __launch_bounds__(256) void k_prep(const float* __restrict__ dw,
                                              const float* __restrict__ gw,
                                              const float* __restrict__ db,
                                              const float* __restrict__ ntl,
                                              const float* __restrict__ leaf,
                                              unsigned short* __restrict__ w_hi,
                                              unsigned short* __restrict__ w_lo,
                                              unsigned short* __restrict__ leafT,
                                              float* __restrict__ it_zb) {
    const int b = blockIdx.x;
    if (b < 192) {
        const int i = b * 256 + threadIdx.x;        // n*1024 + k
        const int n = i >> 10;
        const float v = (n < NDEC) ? dw[i] : gw[i - NDEC * DIN];
        const unsigned short h = f2bf(v);
        w_hi[i] = h;
        w_lo[i] = f2bf(v - bf2f(h));
    } else if (b < 264) {
        const int i  = (b - 192) * 256 + threadIdx.x;   // 0 .. 18431
        const int hq = i % (NH * DOUT);                 // h*512 + d
        const int kq = i / (NH * DOUT);                 // 0..11
        const int h  = hq >> 9, d = hq & 511;
        bf16x8 v;
#pragma unroll
        for (int e = 0; e < 8; ++e)
            v[e] = (short)f2bf(leaf[(size_t)(h * NC + kq * 8 + e) * DOUT + d]);
        *(bf16x8*)(leafT + (size_t)hq * NC + kq * 8) = v;
    } else {
        const int i = threadIdx.x;
        if (i < NDEC) {
            const float v  = ntl[i] + 0.5413f;
            const float sp = (v > 20.0f) ? v : logf(1.0f + expf(v));
            const float it = 1.0f / sp;
            it_zb[i]        = it;            // inv_temp
            it_zb[NDEC + i] = db[i] * it;    // pre-scaled bias
        }
    }
}

// ---------------------------------------------------------------------------
// k_fused: per block = 16 rows, 4 waves.
//   phase 1: GEMM1  (wave w covers K-chunk [w*256,(w+1)*256), split-bf16 MFMA)
//   phase 2: LDS reduce + epilogue (sigmoid/leaf/softmax) -> C_lds bf16[16][96]
//   phase 3: GEMM2  (wave w covers 24 of the 96 16-col output fragments)
// ---------------------------------------------------------------------------
__global__ __launch_bounds__(256) void k_fused(const float* __restrict__ x,
                                               const unsigned short* __restrict__ w_hi,
                                               const unsigned short* __restrict__ w_lo,
                                               const unsigned short* __restrict__ leafT,
                                               const float* __restrict__ it_zb,
                                               const float* __restrict__ gb,
                                               float* __restrict__ out) {
    __shared__ float Lred[4][NCOL][17];                 // padded: conflict-free writes
    __shared__ __align__(16) unsigned short Cl[16][CLP];

    const int tid  = threadIdx.x;
    const int wv   = tid >> 6, lane = tid & 63;
    const int m    = lane & 15;                         // MFMA m / n lane index
    const int kq   = lane >> 4;                         // k quarter (0..3)
    const int row0 = blockIdx.x * 16;

    // ---------------- phase 1: GEMM1 over this wave's K-chunk ----------------
    f32x4 acc[3];
#pragma unroll
    for (int nf = 0; nf < 3; ++nf)
#pragma unroll
        for (int r = 0; r < 4; ++r) acc[nf][r] = 0.0f;

    const float*          xp  = x    + (size_t)(row0 + m) * DIN + wv * 256 + kq * 8;
    const unsigned short* whp = w_hi + (size_t)m * DIN + wv * 256 + kq * 8;
    const unsigned short* wlp = w_lo + (size_t)m * DIN + wv * 256 + kq * 8;

#pragma unroll
    for (int ks = 0; ks < 8; ++ks) {
        const float4 xa = *(const float4*)(xp + ks * 32);
        const float4 xb = *(const float4*)(xp + ks * 32 + 4);
        bf16x8 xhi, xlo;
        split8(xa, xb, xhi, xlo);
#pragma unroll
        for (int nf = 0; nf < 3; ++nf) {
            const bf16x8 whi = *(const bf16x8*)(whp + (size_t)nf * 16 * DIN + ks * 32);
            const bf16x8 wlo = *(const bf16x8*)(wlp + (size_t)nf * 16 * DIN + ks * 32);
            acc[nf] = __builtin_amdgcn_mfma_f32_16x16x32_bf16(xhi, whi, acc[nf], 0, 0, 0);
            acc[nf] = __builtin_amdgcn_mfma_f32_16x16x32_bf16(xlo, whi, acc[nf], 0, 0, 0);
            acc[nf] = __builtin_amdgcn_mfma_f32_16x16x32_bf16(xhi, wlo, acc[nf], 0, 0, 0);
        }
    }
    // D layout: col(lane&15) = n, row = kq*4 + r
#pragma unroll
    for (int nf = 0; nf < 3; ++nf)
#pragma unroll
        for (int r = 0; r < 4; ++r)
            Lred[wv][nf * 16 + m][kq * 4 + r] = acc[nf][r];
    __syncthreads();

    // ---------------- phase 2: reduce + epilogue ----------------
    {
        const int erow = tid >> 4;      // 0..15  (row within block)
        const int slot = tid & 15;      // 0..11 = tree, 12..15 idle
        float lg0 = 0.f, lg1 = 0.f, lg2 = 0.f, g = -1e30f;
        if (slot < NT) {
            float lgg = 0.f;
#pragma unroll
            for (int w = 0; w < 4; ++w) {
                lg0 += Lred[w][slot * 3 + 0][erow];
                lg1 += Lred[w][slot * 3 + 1][erow];
                lg2 += Lred[w][slot * 3 + 2][erow];
                lgg += Lred[w][NDEC + slot][erow];
            }
            g = lgg + gb[slot];
        }
        // softmax over the 16-lane row-group (slots >= 12 contribute 0)
        float mx = g;
#pragma unroll
        for (int off = 1; off < 16; off <<= 1) mx = fmaxf(mx, __shfl_xor(mx, off, 16));
        const float e = (slot < NT) ? expf(g - mx) : 0.f;
        float s = e;
#pragma unroll
        for (int off = 1; off < 16; off <<= 1) s += __shfl_xor(s, off, 16);
        if (slot < NT) {
            const float wt = e * __builtin_amdgcn_rcpf(s);
            const float z0 = lg0 * it_zb[slot * 3 + 0] + it_zb[NDEC + slot * 3 + 0];
            const float z1 = lg1 * it_zb[slot * 3 + 1] + it_zb[NDEC + slot * 3 + 1];
            const float z2 = lg2 * it_zb[slot * 3 + 2] + it_zb[NDEC + slot * 3 + 2];
            const float d0 = __builtin_amdgcn_rcpf(1.0f + expf(-z0));
            const float d1 = __builtin_amdgcn_rcpf(1.0f + expf(-z1));
            const float d2 = __builtin_amdgcn_rcpf(1.0f + expf(-z2));
            float c[8];
#pragma unroll
            for (int l = 0; l < 8; ++l) {
                const float p0 = (l & 4) ? (1.0f - d0) : d0;
                const float p1 = (l & 2) ? (1.0f - d1) : d1;
                const float p2 = (l & 1) ? (1.0f - d2) : d2;
                c[l] = wt * p0 * p1 * p2;
            }
            union { unsigned u[4]; bf16x8 v; } P;
            P.u[0] = cvt_pk(c[0], c[1]); P.u[1] = cvt_pk(c[2], c[3]);
            P.u[2] = cvt_pk(c[4], c[5]); P.u[3] = cvt_pk(c[6], c[7]);
            *(bf16x8*)&Cl[erow][slot * 8] = P.v;
        }
    }
    __syncthreads();

    // ---------------- phase 3: GEMM2, wave covers 24 of 96 col-fragments ----
    bf16x8 afr[3];
#pragma unroll
    for (int ks = 0; ks < 3; ++ks)
        afr[ks] = *(const bf16x8*)&Cl[m][ks * 32 + kq * 8];

#pragma unroll
    for (int i = 0; i < 24; ++i) {
        const int f   = wv * 24 + i;          // 0..95
        const int h   = f >> 5;               // 512/16 = 32 frags per head
        const int d0c = (f & 31) * 16;
        const unsigned short* bp = leafT + ((size_t)h * DOUT + d0c + m) * NC + kq * 8;
        f32x4 a;
#pragma unroll
        for (int r = 0; r < 4; ++r) a[r] = 0.0f;
#pragma unroll
        for (int ks = 0; ks < 3; ++ks) {
            const bf16x8 bfr = *(const bf16x8*)(bp + ks * 32);
            a = __builtin_amdgcn_mfma_f32_16x16x32_bf16(afr[ks], bfr, a, 0, 0, 0);
        }
        float* op = out + ((size_t)h * NROWS + row0 + kq * 4) * DOUT + d0c + m;
#pragma unroll
        for (int r = 0; r < 4; ++r) op[(size_t)r * DOUT] = a[r];
    }
}

extern "C" void kernel_launch(void* const* d_in, const int* in_sizes, int n_in,
                              void* d_out, int out_size, void* d_ws, size_t ws_size,
                              hipStream_t stream) {
    const float* x    = (const float*)d_in[0];
    const float* dw   = (const float*)d_in[1];
    const float* db   = (const float*)d_in[2];
    const float* ntl  = (const float*)d_in[3];
    const float* gw   = (const float*)d_in[4];
    const float* gb   = (const float*)d_in[5];
    const float* leaf = (const float*)d_in[6];
    float* out = (float*)d_out;

    // workspace carve (byte offsets, all 16B-aligned)
    char* ws = (char*)d_ws;
    unsigned short* w_hi  = (unsigned short*)(ws);            // 48*1024*2 =  98304 B
    unsigned short* w_lo  = (unsigned short*)(ws + 98304);    //              98304 B
    unsigned short* leafT = (unsigned short*)(ws + 196608);   // 3*512*96*2 = 294912 B
    float*          it_zb = (float*)(ws + 491520);            // 72*4       =    288 B

    k_prep<<<265, 256, 0, stream>>>(dw, gw, db, ntl, leaf, w_hi, w_lo, leafT, it_zb);
    k_fused<<<NROWS / 16, 256, 0, stream>>>(x, w_hi, w_lo, leafT, it_zb, gb, out);
}